// Round 5
// baseline (328.995 us; speedup 1.0000x reference)
//
#include <hip/hip_runtime.h>
#include <math.h>

// VQ-AE forward. bf16 MFMA only for enc1 / dec2 / quant-argmin (R2-proven);
// mid-chain (h1 storage, z-GEMM, dec1, h2 storage) is fp32 for accuracy.
// ws: acc[1024] f32 | cbb[1024*32] bf16 | cn_g[1024] f32 | h1[65536*128] f32 | h2[...] f32
// acc: [0..127] sum1, [128..255] sumsq1, [256..383] sum2, [384..511] sumsq2,
//      [512] min-dist sum, [513] sq-diff sum

typedef __attribute__((ext_vector_type(8))) short bf8;
typedef __attribute__((ext_vector_type(4))) float f4a;

__device__ __forceinline__ unsigned short f2bf(float f) {
    unsigned u = __float_as_uint(f);
    u += 0x7fffu + ((u >> 16) & 1u);   // RNE
    return (unsigned short)(u >> 16);
}
__device__ __forceinline__ unsigned pack2(float a, float b) {
    return (unsigned)f2bf(a) | ((unsigned)f2bf(b) << 16);
}

// ======== K0: zero acc + codebook -> bf16 + fp32 norms ========
__global__ __launch_bounds__(256) void k_prep(const float* __restrict__ cb,
                                              float* __restrict__ acc,
                                              unsigned short* __restrict__ cbb,
                                              float* __restrict__ cn_g) {
    const int b = blockIdx.x, t = threadIdx.x;
    if (b < 4) {
        const int cw = (b << 8) + t;
        const float* p = cb + (size_t)cw * 32;
        unsigned out[16];
        float n = 0.f;
#pragma unroll
        for (int i = 0; i < 8; ++i) {
            float4 v = *(const float4*)(p + (i << 2));
            n = fmaf(v.x, v.x, n); n = fmaf(v.y, v.y, n);
            n = fmaf(v.z, v.z, n); n = fmaf(v.w, v.w, n);
            out[2 * i]     = pack2(v.x, v.y);
            out[2 * i + 1] = pack2(v.z, v.w);
        }
#pragma unroll
        for (int i = 0; i < 4; ++i)
            *(uint4*)(cbb + (size_t)cw * 32 + (i << 3)) =
                make_uint4(out[4 * i], out[4 * i + 1], out[4 * i + 2], out[4 * i + 3]);
        cn_g[cw] = n;
    } else {
        for (int i = t; i < 1024; i += 256) acc[i] = 0.f;
    }
}

// ======== K1: h1 = fp32(X@w1 + b1) (bf16 MFMA), + column sum/sumsq ========
__global__ __launch_bounds__(256) void k_enc1(const float* __restrict__ X,
                                              const float* __restrict__ w1,
                                              const float* __restrict__ b1,
                                              float* __restrict__ h1,
                                              float* __restrict__ acc_g) {
    __shared__ unsigned short As[128 * 72];
    __shared__ unsigned short Bs[128 * 72];
    __shared__ float sred[2 * 4 * 128];   // [stat][wave][col]
    const int t = threadIdx.x;
    const int row0 = blockIdx.x << 7;
    const int w = t >> 6, lane = t & 63, quad = lane >> 4, lcol = lane & 15;
    f4a acc[2][8];
#pragma unroll
    for (int i = 0; i < 2; i++)
#pragma unroll
        for (int j = 0; j < 8; j++) acc[i][j] = (f4a){0.f, 0.f, 0.f, 0.f};

    const int bn = t & 127, bkg = t >> 7;
    for (int c = 0; c < 8; ++c) {
        const int k0 = c << 6;
        __syncthreads();
#pragma unroll
        for (int i = 0; i < 8; ++i) {
            int fidx = (i << 8) + t;
            int r = fidx >> 4, kq = (fidx & 15) << 2;
            float4 v = *(const float4*)(X + (size_t)(row0 + r) * 512 + k0 + kq);
            *(uint2*)&As[r * 72 + kq] = make_uint2(pack2(v.x, v.y), pack2(v.z, v.w));
        }
#pragma unroll
        for (int i = 0; i < 8; ++i) {
            int k = (bkg << 5) + (i << 2);
            const float* p = w1 + (size_t)(k0 + k) * 128 + bn;
            float a0 = p[0], a1 = p[128], a2 = p[256], a3 = p[384];
            *(uint2*)&Bs[bn * 72 + k] = make_uint2(pack2(a0, a1), pack2(a2, a3));
        }
        __syncthreads();
#pragma unroll
        for (int ks = 0; ks < 2; ++ks) {
            const bf8 a0 = *(const bf8*)&As[(w * 32 + lcol) * 72 + (ks << 5) + (quad << 3)];
            const bf8 a1 = *(const bf8*)&As[(w * 32 + 16 + lcol) * 72 + (ks << 5) + (quad << 3)];
#pragma unroll
            for (int nt = 0; nt < 8; ++nt) {
                const bf8 bb = *(const bf8*)&Bs[(nt * 16 + lcol) * 72 + (ks << 5) + (quad << 3)];
                acc[0][nt] = __builtin_amdgcn_mfma_f32_16x16x32_bf16(a0, bb, acc[0][nt], 0, 0, 0);
                acc[1][nt] = __builtin_amdgcn_mfma_f32_16x16x32_bf16(a1, bb, acc[1][nt], 0, 0, 0);
            }
        }
    }
#pragma unroll
    for (int nt = 0; nt < 8; ++nt) {
        const int gc = (nt << 4) + lcol;
        const float bias = b1[gc];
        float s = 0.f, ss = 0.f;
#pragma unroll
        for (int mt = 0; mt < 2; ++mt) {
            const int rbase = row0 + w * 32 + mt * 16 + (quad << 2);
#pragma unroll
            for (int r = 0; r < 4; ++r) {
                float v = acc[mt][nt][r] + bias;
                h1[(size_t)(rbase + r) * 128 + gc] = v;
                s += v;
                ss = fmaf(v, v, ss);
            }
        }
        s += __shfl_xor(s, 16);  s += __shfl_xor(s, 32);
        ss += __shfl_xor(ss, 16); ss += __shfl_xor(ss, 32);
        if (quad == 0) { sred[w * 128 + gc] = s; sred[512 + w * 128 + gc] = ss; }
    }
    __syncthreads();
    if (t < 128) {
        atomicAdd(&acc_g[t], sred[t] + sred[128 + t] + sred[256 + t] + sred[384 + t]);
        atomicAdd(&acc_g[128 + t], sred[512 + t] + sred[640 + t] + sred[768 + t] + sred[896 + t]);
    }
}

// ======== K2: fused enc2(fp32) + quantize(bf16 argmin, fp32 dist) + dec1(fp32) + stats2 ========
// 512 blocks x 256 thr, 128 rows/block.
__global__ __launch_bounds__(256) void k_mid(const float* __restrict__ h1,
                                             const float* __restrict__ w2e,
                                             const float* __restrict__ b2e,
                                             const float* __restrict__ g1,
                                             const float* __restrict__ be1,
                                             const float* __restrict__ cb,
                                             const unsigned short* __restrict__ cbb,
                                             const float* __restrict__ cn_g,
                                             const float* __restrict__ w1d,
                                             const float* __restrict__ b1d,
                                             float* __restrict__ h2,
                                             float* __restrict__ acc_g) {
    // LDS pool (52736 B), phase-sequenced:
    //  region0 @0     (21504): Ws2 f32[4096] (A) | cs ushort[256*40]+cn f32[256] (B) | W1d f32[4096] (C)
    //  region1 @21504 (16896): zf f32[128*33] (A->recompute) | Qf f32[128*33] (C)
    //  region2 @38400 (10240): zs ushort[128*40] (A->B)
    //  region3 @48640: zn[128] | red[256] | topicsL[128] | sstat[256] | scl[128] | shf[128]
    __shared__ __align__(16) char pool[52736];
    float*          Ws2 = (float*)pool;
    unsigned short* cs  = (unsigned short*)pool;
    float*          cn  = (float*)(pool + 20480);
    float*          W1d = (float*)pool;
    float*          zf  = (float*)(pool + 21504);
    float*          Qf  = (float*)(pool + 21504);
    unsigned short* zs  = (unsigned short*)(pool + 38400);
    float* zn    = (float*)(pool + 48640);
    float* red   = (float*)(pool + 49152);
    int*   topicsL = (int*)(pool + 50176);
    float* sstat = (float*)(pool + 50688);
    float* scl   = (float*)(pool + 51712);
    float* shf   = (float*)(pool + 52224);

    const int t = threadIdx.x;
    const int w = t >> 6, lane = t & 63, quad = lane >> 4, lcol = lane & 15;
    const int row0 = blockIdx.x << 7;

    // --- BN params (enc) + stage Ws2 fp32 ---
    if (t < 128) {
        float mu = acc_g[t] * (1.f / 65536.f);
        float var = fmaf(-mu, mu, acc_g[128 + t] * (1.f / 65536.f));
        float s = g1[t] * rsqrtf(var + 1e-5f);
        scl[t] = s;
        shf[t] = fmaf(-mu, s, be1[t]);
    }
#pragma unroll
    for (int i = 0; i < 16; ++i) Ws2[(i << 8) + t] = w2e[(i << 8) + t];
    __syncthreads();

    // --- Phase A: z = bn_relu(h1) @ w2e + b2e, fp32. 2 halves x 64 rows; 4 thr/row x 8 cols ---
    const int zr = t >> 2, cg = t & 3;
    const float4 bza = *(const float4*)(b2e + (cg << 3));
    const float4 bzb = *(const float4*)(b2e + (cg << 3) + 4);
#pragma unroll
    for (int half = 0; half < 2; ++half) {
        const int row = (half << 6) + zr;
        const float* hrow = h1 + (size_t)(row0 + row) * 128;
        float z[8];
#pragma unroll
        for (int j = 0; j < 8; ++j) z[j] = 0.f;
        for (int k4 = 0; k4 < 32; ++k4) {
            const float4 hv = *(const float4*)(hrow + (k4 << 2));
            const float4 sc = *(const float4*)&scl[k4 << 2];
            const float4 sh = *(const float4*)&shf[k4 << 2];
            float a[4];
            a[0] = fmaxf(fmaf(hv.x, sc.x, sh.x), 0.f);
            a[1] = fmaxf(fmaf(hv.y, sc.y, sh.y), 0.f);
            a[2] = fmaxf(fmaf(hv.z, sc.z, sh.z), 0.f);
            a[3] = fmaxf(fmaf(hv.w, sc.w, sh.w), 0.f);
#pragma unroll
            for (int e = 0; e < 4; ++e) {
                const int k = (k4 << 2) + e;
                const float4 wa = *(const float4*)&Ws2[k * 32 + (cg << 3)];
                const float4 wb = *(const float4*)&Ws2[k * 32 + (cg << 3) + 4];
                z[0] = fmaf(a[e], wa.x, z[0]); z[1] = fmaf(a[e], wa.y, z[1]);
                z[2] = fmaf(a[e], wa.z, z[2]); z[3] = fmaf(a[e], wa.w, z[3]);
                z[4] = fmaf(a[e], wb.x, z[4]); z[5] = fmaf(a[e], wb.y, z[5]);
                z[6] = fmaf(a[e], wb.z, z[6]); z[7] = fmaf(a[e], wb.w, z[7]);
            }
        }
        z[0] += bza.x; z[1] += bza.y; z[2] += bza.z; z[3] += bza.w;
        z[4] += bzb.x; z[5] += bzb.y; z[6] += bzb.z; z[7] += bzb.w;
        float pn = 0.f;
#pragma unroll
        for (int j = 0; j < 8; ++j) {
            zf[row * 33 + (cg << 3) + j] = z[j];
            pn = fmaf(z[j], z[j], pn);
        }
        *(uint4*)&zs[row * 40 + (cg << 3)] =
            make_uint4(pack2(z[0], z[1]), pack2(z[2], z[3]),
                       pack2(z[4], z[5]), pack2(z[6], z[7]));
        pn += __shfl_xor(pn, 1);
        pn += __shfl_xor(pn, 2);
        if (cg == 0) zn[row] = pn;
    }
    __syncthreads();

    // --- Phase B: quant sweep (bf16 proxy for argmin only) ---
    bf8 af[2];
    af[0] = *(const bf8*)&zs[(w * 32 + lcol) * 40 + (quad << 3)];
    af[1] = *(const bf8*)&zs[(w * 32 + 16 + lcol) * 40 + (quad << 3)];
    float best[2][4];
    int bidx[2][4];
#pragma unroll
    for (int mt = 0; mt < 2; ++mt)
#pragma unroll
        for (int r = 0; r < 4; ++r) { best[mt][r] = 3.4e38f; bidx[mt][r] = 0; }
    const f4a zero4 = {0.f, 0.f, 0.f, 0.f};

    for (int cp = 0; cp < 4; ++cp) {
        __syncthreads();
#pragma unroll
        for (int i = 0; i < 4; ++i) {   // b128 copy of prepped bf16 codebook
            int idx = (i << 8) + t;
            int r = idx >> 2, kq = (idx & 3) << 3;
            *(uint4*)&cs[r * 40 + kq] = *(const uint4*)(cbb + (size_t)((cp << 8) + r) * 32 + kq);
        }
        cn[t] = cn_g[(cp << 8) + t];
        __syncthreads();
        bf8 bb = *(const bf8*)&cs[lcol * 40 + (quad << 3)];
        float cnv = cn[lcol];
        for (int ch = 0; ch < 16; ++ch) {
            const int nn = ((ch + 1) & 15) << 4;
            const bf8 bb_n = *(const bf8*)&cs[(nn + lcol) * 40 + (quad << 3)];
            const float cn_n = cn[nn + lcol];
            const int cidx = (cp << 8) + (ch << 4) + lcol;
#pragma unroll
            for (int mt = 0; mt < 2; ++mt) {
                f4a a = __builtin_amdgcn_mfma_f32_16x16x32_bf16(af[mt], bb, zero4, 0, 0, 0);
#pragma unroll
                for (int r = 0; r < 4; ++r) {
                    float d = fmaf(-2.f, a[r], cnv);   // proxy: cn - 2 z.c (zn const per row)
                    if (d < best[mt][r]) { best[mt][r] = d; bidx[mt][r] = cidx; }
                }
            }
            bb = bb_n; cnv = cn_n;
        }
    }
    // cross-lane argmin (first-index tie-break) -> all 16 lanes of each group converge
#pragma unroll
    for (int off = 1; off < 16; off <<= 1) {
#pragma unroll
        for (int mt = 0; mt < 2; ++mt)
#pragma unroll
            for (int r = 0; r < 4; ++r) {
                float ob = __shfl_xor(best[mt][r], off);
                int oi = __shfl_xor(bidx[mt][r], off);
                if (ob < best[mt][r] || (ob == best[mt][r] && oi < bidx[mt][r])) {
                    best[mt][r] = ob; bidx[mt][r] = oi;
                }
            }
    }
    // exact fp32 distance of the selected codeword (fp32 z from zf, fp32 cb)
    float lsum = 0.f;
#pragma unroll
    for (int mt = 0; mt < 2; ++mt) {
#pragma unroll
        for (int r = 0; r < 4; ++r) {
            const int rowl = w * 32 + mt * 16 + (quad << 2) + r;
            const int ti = bidx[mt][r];
            const float* cp_ = cb + (size_t)ti * 32;
            float d0 = zf[rowl * 33 + lcol] - cp_[lcol];
            float d1 = zf[rowl * 33 + 16 + lcol] - cp_[16 + lcol];
            float p = fmaf(d0, d0, d1 * d1);
            p += __shfl_xor(p, 1); p += __shfl_xor(p, 2);
            p += __shfl_xor(p, 4); p += __shfl_xor(p, 8);
            if (lcol == 0) {
                topicsL[rowl] = ti;
                lsum += p;
            }
        }
    }
    red[t] = lsum;
    __syncthreads();
    for (int s = 128; s > 0; s >>= 1) {
        if (t < s) red[t] += red[t + s];
        __syncthreads();
    }
    if (t == 0) atomicAdd(acc_g + 512, red[0]);
    // (reduce loop ends with __syncthreads: zf reads done, cs/sweep done -> safe to overlay)

    // --- Phase C: gather fp32 codewords; stage W1d fp32; dec1 fp32 + stats2 ---
#pragma unroll
    for (int i = 0; i < 16; ++i) {
        int idx = (i << 8) + t;
        int r = idx >> 5, c = idx & 31;
        Qf[r * 33 + c] = cb[(size_t)topicsL[r] * 32 + c];
    }
#pragma unroll
    for (int i = 0; i < 16; ++i) W1d[(i << 8) + t] = w1d[(i << 8) + t];
    sstat[t] = 0.f;
    __syncthreads();

    const int rl = t >> 5, c4 = t & 31;
    const float4 b1v = *(const float4*)(b1d + (c4 << 2));
    float s4[4] = {0.f, 0.f, 0.f, 0.f}, ss4[4] = {0.f, 0.f, 0.f, 0.f};
    for (int pass = 0; pass < 16; ++pass) {
        const int rowl = (pass << 3) + rl;
        float4 o = b1v;
#pragma unroll
        for (int j = 0; j < 32; ++j) {
            const float q = Qf[rowl * 33 + j];
            const float4 wv = *(const float4*)&W1d[j * 128 + (c4 << 2)];
            o.x = fmaf(q, wv.x, o.x); o.y = fmaf(q, wv.y, o.y);
            o.z = fmaf(q, wv.z, o.z); o.w = fmaf(q, wv.w, o.w);
        }
        *(float4*)(h2 + (size_t)(row0 + rowl) * 128 + (c4 << 2)) = o;
        s4[0] += o.x; s4[1] += o.y; s4[2] += o.z; s4[3] += o.w;
        ss4[0] = fmaf(o.x, o.x, ss4[0]); ss4[1] = fmaf(o.y, o.y, ss4[1]);
        ss4[2] = fmaf(o.z, o.z, ss4[2]); ss4[3] = fmaf(o.w, o.w, ss4[3]);
    }
#pragma unroll
    for (int j = 0; j < 4; ++j) {
        atomicAdd(&sstat[(c4 << 2) + j], s4[j]);
        atomicAdd(&sstat[128 + (c4 << 2) + j], ss4[j]);
    }
    __syncthreads();
    if (t < 128) {
        atomicAdd(&acc_g[256 + t], sstat[t]);
        atomicAdd(&acc_g[384 + t], sstat[128 + t]);
    }
}

// ======== K3: X_ = relu(bn(h2))@dw2 + db2 ; accumulate sum((X_-X)^2) ========
// 512 thr (8 waves, 2x4), tile 128M x 256N, BK=32 (4 chunks), grid (512, 2).
__global__ __launch_bounds__(512) void k_dec2(const float* __restrict__ h2,
                                              float* acc_g,
                                              const float* __restrict__ g,
                                              const float* __restrict__ be,
                                              const float* __restrict__ w2,
                                              const float* __restrict__ b2,
                                              const float* __restrict__ X) {
    __shared__ unsigned short As[128 * 40];
    __shared__ unsigned short Bs[256 * 40];
    __shared__ float scl[128], shf[128];
    __shared__ float red[512];
    const int t = threadIdx.x;
    if (t < 128) {
        float mu = acc_g[256 + t] * (1.f / 65536.f);
        float var = fmaf(-mu, mu, acc_g[384 + t] * (1.f / 65536.f));
        float s = g[t] * rsqrtf(var + 1e-5f);
        scl[t] = s;
        shf[t] = fmaf(-mu, s, be[t]);
    }
    const int row0 = blockIdx.x << 7;
    const int col0 = blockIdx.y << 8;
    const int w = t >> 6, lane = t & 63, quad = lane >> 4, lcol = lane & 15;
    const int wm = w & 1, wn = w >> 1;
    f4a acc[4][4];
#pragma unroll
    for (int i = 0; i < 4; i++)
#pragma unroll
        for (int j = 0; j < 4; j++) acc[i][j] = (f4a){0.f, 0.f, 0.f, 0.f};
    __syncthreads();

    const int bn = t & 255, bkg = t >> 8;
    for (int c = 0; c < 4; ++c) {
        const int k0 = c << 5;
        if (c) __syncthreads();
        // A: fp32 h2 tile, BN+ReLU fused, -> bf16
#pragma unroll
        for (int i = 0; i < 2; ++i) {
            int fidx = (i << 9) + t;
            int r = fidx >> 3, kq = (fidx & 7) << 2;
            float4 v = *(const float4*)(h2 + (size_t)(row0 + r) * 128 + k0 + kq);
            v.x = fmaxf(fmaf(v.x, scl[k0 + kq + 0], shf[k0 + kq + 0]), 0.f);
            v.y = fmaxf(fmaf(v.y, scl[k0 + kq + 1], shf[k0 + kq + 1]), 0.f);
            v.z = fmaxf(fmaf(v.z, scl[k0 + kq + 2], shf[k0 + kq + 2]), 0.f);
            v.w = fmaxf(fmaf(v.w, scl[k0 + kq + 3], shf[k0 + kq + 3]), 0.f);
            *(uint2*)&As[r * 40 + kq] = make_uint2(pack2(v.x, v.y), pack2(v.z, v.w));
        }
        // B: w2 chunk [32k][256n] -> Bs[n][k]
#pragma unroll
        for (int i = 0; i < 4; ++i) {
            int k = (bkg << 4) + (i << 2);
            const float* p = w2 + (size_t)(k0 + k) * 512 + col0 + bn;
            float a0 = p[0], a1 = p[512], a2 = p[1024], a3 = p[1536];
            *(uint2*)&Bs[bn * 40 + k] = make_uint2(pack2(a0, a1), pack2(a2, a3));
        }
        __syncthreads();
        bf8 af[4];
#pragma unroll
        for (int mt = 0; mt < 4; ++mt)
            af[mt] = *(const bf8*)&As[(wm * 64 + mt * 16 + lcol) * 40 + (quad << 3)];
#pragma unroll
        for (int nt = 0; nt < 4; ++nt) {
            const bf8 bb = *(const bf8*)&Bs[(wn * 64 + nt * 16 + lcol) * 40 + (quad << 3)];
#pragma unroll
            for (int mt = 0; mt < 4; ++mt)
                acc[mt][nt] = __builtin_amdgcn_mfma_f32_16x16x32_bf16(af[mt], bb, acc[mt][nt], 0, 0, 0);
        }
    }
    float lsum = 0.f;
#pragma unroll
    for (int nt = 0; nt < 4; ++nt) {
        const int gc = col0 + wn * 64 + nt * 16 + lcol;
        const float bias = b2[gc];
#pragma unroll
        for (int mt = 0; mt < 4; ++mt) {
            const int rbase = row0 + wm * 64 + mt * 16 + (quad << 2);
#pragma unroll
            for (int r = 0; r < 4; ++r) {
                float val = acc[mt][nt][r] + bias;
                float d = val - X[(size_t)(rbase + r) * 512 + gc];
                lsum = fmaf(d, d, lsum);
            }
        }
    }
    red[t] = lsum;
    __syncthreads();
    for (int s = 256; s > 0; s >>= 1) {
        if (t < s) red[t] += red[t + s];
        __syncthreads();
    }
    if (t == 0) atomicAdd(acc_g + 513, red[0]);
}

__global__ void k_final(const float* __restrict__ acc, float* __restrict__ out) {
    if (threadIdx.x == 0) out[0] = 2.f * acc[512] + sqrtf(acc[513]);
}

extern "C" void kernel_launch(void* const* d_in, const int* in_sizes, int n_in,
                              void* d_out, int out_size, void* d_ws, size_t ws_size,
                              hipStream_t stream) {
    const float* X       = (const float*)d_in[0];
    const float* enc_w1  = (const float*)d_in[1];
    const float* enc_b1  = (const float*)d_in[2];
    const float* enc_g1  = (const float*)d_in[3];
    const float* enc_be1 = (const float*)d_in[4];
    const float* enc_w2  = (const float*)d_in[5];
    const float* enc_b2  = (const float*)d_in[6];
    const float* dec_w1  = (const float*)d_in[7];
    const float* dec_b1  = (const float*)d_in[8];
    const float* dec_g1  = (const float*)d_in[9];
    const float* dec_be1 = (const float*)d_in[10];
    const float* dec_w2  = (const float*)d_in[11];
    const float* dec_b2  = (const float*)d_in[12];
    const float* cb      = (const float*)d_in[13];
    float* out = (float*)d_out;

    float* acc = (float*)d_ws;                               // 1024 f32
    unsigned short* cbb = (unsigned short*)(acc + 1024);     // 1024*32 bf16
    float* cn_g = (float*)(cbb + 1024 * 32);                 // 1024 f32
    float* h1 = cn_g + 1024;                                 // 65536*128 f32
    float* h2 = h1 + (size_t)65536 * 128;                    // 65536*128 f32

    k_prep<<<5, 256, 0, stream>>>(cb, acc, cbb, cn_g);
    k_enc1<<<512, 256, 0, stream>>>(X, enc_w1, enc_b1, h1, acc);
    k_mid<<<512, 256, 0, stream>>>(h1, enc_w2, enc_b2, enc_g1, enc_be1,
                                   cb, cbb, cn_g, dec_w1, dec_b1, h2, acc);
    k_dec2<<<dim3(512, 2), 512, 0, stream>>>(h2, acc, dec_g1, dec_be1, dec_w2, dec_b2, X);
    k_final<<<1, 64, 0, stream>>>(acc, out);
}

// Round 6
// 323.782 us; speedup vs baseline: 1.0161x; 1.0161x over previous
//
#include <hip/hip_runtime.h>
#include <math.h>

// VQ-AE forward. z-path (h1, z-GEMM, selected-distance) fp32 (accuracy-critical:
// output ~2.5e6 is dominated by 2*z_loss). Post-topics path (dec1, h2, dec2) is
// bf16 MFMA (contributes only via sqrt-term ~5.8e3 -> absmax impact O(10)).
// ws: acc[1024] f32 | cbb[1024*32] bf16 | cn_g[1024] f32 | h1[65536*128] f32 | h2b[...] bf16
// acc: [0..127] sum1, [128..255] sumsq1, [256..383] sum2, [384..511] sumsq2,
//      [512] min-dist sum, [513] sq-diff sum

typedef __attribute__((ext_vector_type(8))) short bf8;
typedef __attribute__((ext_vector_type(4))) float f4a;

__device__ __forceinline__ unsigned short f2bf(float f) {
    unsigned u = __float_as_uint(f);
    u += 0x7fffu + ((u >> 16) & 1u);   // RNE
    return (unsigned short)(u >> 16);
}
__device__ __forceinline__ unsigned pack2(float a, float b) {
    return (unsigned)f2bf(a) | ((unsigned)f2bf(b) << 16);
}
__device__ __forceinline__ void unpack2(unsigned p, float& lo, float& hi) {
    lo = __uint_as_float(p << 16);
    hi = __uint_as_float(p & 0xffff0000u);
}

// ======== K0: zero acc + codebook -> bf16 + fp32 norms ========
__global__ __launch_bounds__(256) void k_prep(const float* __restrict__ cb,
                                              float* __restrict__ acc,
                                              unsigned short* __restrict__ cbb,
                                              float* __restrict__ cn_g) {
    const int b = blockIdx.x, t = threadIdx.x;
    if (b < 4) {
        const int cw = (b << 8) + t;
        const float* p = cb + (size_t)cw * 32;
        unsigned out[16];
        float n = 0.f;
#pragma unroll
        for (int i = 0; i < 8; ++i) {
            float4 v = *(const float4*)(p + (i << 2));
            n = fmaf(v.x, v.x, n); n = fmaf(v.y, v.y, n);
            n = fmaf(v.z, v.z, n); n = fmaf(v.w, v.w, n);
            out[2 * i]     = pack2(v.x, v.y);
            out[2 * i + 1] = pack2(v.z, v.w);
        }
#pragma unroll
        for (int i = 0; i < 4; ++i)
            *(uint4*)(cbb + (size_t)cw * 32 + (i << 3)) =
                make_uint4(out[4 * i], out[4 * i + 1], out[4 * i + 2], out[4 * i + 3]);
        cn_g[cw] = n;
    } else {
        for (int i = t; i < 1024; i += 256) acc[i] = 0.f;
    }
}

// ======== K1: h1 = fp32(X@w1 + b1) (bf16 MFMA), + column sum/sumsq ========
__global__ __launch_bounds__(256) void k_enc1(const float* __restrict__ X,
                                              const float* __restrict__ w1,
                                              const float* __restrict__ b1,
                                              float* __restrict__ h1,
                                              float* __restrict__ acc_g) {
    __shared__ unsigned short As[128 * 72];
    __shared__ unsigned short Bs[128 * 72];
    __shared__ float sred[2 * 4 * 128];   // [stat][wave][col]
    const int t = threadIdx.x;
    const int row0 = blockIdx.x << 7;
    const int w = t >> 6, lane = t & 63, quad = lane >> 4, lcol = lane & 15;
    f4a acc[2][8];
#pragma unroll
    for (int i = 0; i < 2; i++)
#pragma unroll
        for (int j = 0; j < 8; j++) acc[i][j] = (f4a){0.f, 0.f, 0.f, 0.f};

    const int bn = t & 127, bkg = t >> 7;
    for (int c = 0; c < 8; ++c) {
        const int k0 = c << 6;
        __syncthreads();
#pragma unroll
        for (int i = 0; i < 8; ++i) {
            int fidx = (i << 8) + t;
            int r = fidx >> 4, kq = (fidx & 15) << 2;
            float4 v = *(const float4*)(X + (size_t)(row0 + r) * 512 + k0 + kq);
            *(uint2*)&As[r * 72 + kq] = make_uint2(pack2(v.x, v.y), pack2(v.z, v.w));
        }
#pragma unroll
        for (int i = 0; i < 8; ++i) {
            int k = (bkg << 5) + (i << 2);
            const float* p = w1 + (size_t)(k0 + k) * 128 + bn;
            float a0 = p[0], a1 = p[128], a2 = p[256], a3 = p[384];
            *(uint2*)&Bs[bn * 72 + k] = make_uint2(pack2(a0, a1), pack2(a2, a3));
        }
        __syncthreads();
#pragma unroll
        for (int ks = 0; ks < 2; ++ks) {
            const bf8 a0 = *(const bf8*)&As[(w * 32 + lcol) * 72 + (ks << 5) + (quad << 3)];
            const bf8 a1 = *(const bf8*)&As[(w * 32 + 16 + lcol) * 72 + (ks << 5) + (quad << 3)];
#pragma unroll
            for (int nt = 0; nt < 8; ++nt) {
                const bf8 bb = *(const bf8*)&Bs[(nt * 16 + lcol) * 72 + (ks << 5) + (quad << 3)];
                acc[0][nt] = __builtin_amdgcn_mfma_f32_16x16x32_bf16(a0, bb, acc[0][nt], 0, 0, 0);
                acc[1][nt] = __builtin_amdgcn_mfma_f32_16x16x32_bf16(a1, bb, acc[1][nt], 0, 0, 0);
            }
        }
    }
#pragma unroll
    for (int nt = 0; nt < 8; ++nt) {
        const int gc = (nt << 4) + lcol;
        const float bias = b1[gc];
        float s = 0.f, ss = 0.f;
#pragma unroll
        for (int mt = 0; mt < 2; ++mt) {
            const int rbase = row0 + w * 32 + mt * 16 + (quad << 2);
#pragma unroll
            for (int r = 0; r < 4; ++r) {
                float v = acc[mt][nt][r] + bias;
                h1[(size_t)(rbase + r) * 128 + gc] = v;
                s += v;
                ss = fmaf(v, v, ss);
            }
        }
        s += __shfl_xor(s, 16);  s += __shfl_xor(s, 32);
        ss += __shfl_xor(ss, 16); ss += __shfl_xor(ss, 32);
        if (quad == 0) { sred[w * 128 + gc] = s; sred[512 + w * 128 + gc] = ss; }
    }
    __syncthreads();
    if (t < 128) {
        atomicAdd(&acc_g[t], sred[t] + sred[128 + t] + sred[256 + t] + sred[384 + t]);
        atomicAdd(&acc_g[128 + t], sred[512 + t] + sred[640 + t] + sred[768 + t] + sred[896 + t]);
    }
}

// ======== K2: fused enc2(fp32) + quantize(bf16 argmin, fp32 dist) + dec1(bf16 MFMA) ========
// 512 blocks x 256 thr, 128 rows/block.
__global__ __launch_bounds__(256) void k_mid(const float* __restrict__ h1,
                                             const float* __restrict__ w2e,
                                             const float* __restrict__ b2e,
                                             const float* __restrict__ g1,
                                             const float* __restrict__ be1,
                                             const float* __restrict__ cb,
                                             const unsigned short* __restrict__ cbb,
                                             const float* __restrict__ cn_g,
                                             const float* __restrict__ w1d,
                                             const float* __restrict__ b1d,
                                             unsigned short* __restrict__ h2b,
                                             float* __restrict__ acc_g) {
    // LDS pool (52736 B), phase-sequenced:
    //  region0 @0     (21504): Ws2 f32[4096] (A) | cs us[256*40]+cn f32[256] (B)
    //                          | W1dT us[128*40] + sstat2 f32[1024] (C)
    //  region1 @21504 (16896): zf f32[128*33] (A->recompute) | Qs us[128*40] (C)
    //  region2 @38400 (10240): zs us[128*40] (A->B frags)
    //  region3 @48640: zn[128] | red[256] | topicsL[128] | (pad) | scl[128] | shf[128]
    __shared__ __align__(16) char pool[52736];
    float*          Ws2 = (float*)pool;
    unsigned short* cs  = (unsigned short*)pool;
    float*          cn  = (float*)(pool + 20480);
    unsigned short* W1dT = (unsigned short*)pool;
    float*          sstat2 = (float*)(pool + 10240);
    float*          zf  = (float*)(pool + 21504);
    unsigned short* Qs  = (unsigned short*)(pool + 21504);
    unsigned short* zs  = (unsigned short*)(pool + 38400);
    float* zn    = (float*)(pool + 48640);
    float* red   = (float*)(pool + 49152);
    int*   topicsL = (int*)(pool + 50176);
    float* scl   = (float*)(pool + 51712);
    float* shf   = (float*)(pool + 52224);

    const int t = threadIdx.x;
    const int w = t >> 6, lane = t & 63, quad = lane >> 4, lcol = lane & 15;
    const int row0 = blockIdx.x << 7;

    // --- BN params (enc) + stage Ws2 fp32 ---
    if (t < 128) {
        float mu = acc_g[t] * (1.f / 65536.f);
        float var = fmaf(-mu, mu, acc_g[128 + t] * (1.f / 65536.f));
        float s = g1[t] * rsqrtf(var + 1e-5f);
        scl[t] = s;
        shf[t] = fmaf(-mu, s, be1[t]);
    }
#pragma unroll
    for (int i = 0; i < 16; ++i) Ws2[(i << 8) + t] = w2e[(i << 8) + t];
    __syncthreads();

    // --- Phase A: z = bn_relu(h1) @ w2e + b2e, fp32. 2 halves x 64 rows; 4 thr/row x 8 cols ---
    const int zr = t >> 2, cg = t & 3;
    const float4 bza = *(const float4*)(b2e + (cg << 3));
    const float4 bzb = *(const float4*)(b2e + (cg << 3) + 4);
#pragma unroll
    for (int half = 0; half < 2; ++half) {
        const int row = (half << 6) + zr;
        const float* hrow = h1 + (size_t)(row0 + row) * 128;
        float z[8];
#pragma unroll
        for (int j = 0; j < 8; ++j) z[j] = 0.f;
        for (int k4 = 0; k4 < 32; ++k4) {
            const float4 hv = *(const float4*)(hrow + (k4 << 2));
            const float4 sc = *(const float4*)&scl[k4 << 2];
            const float4 sh = *(const float4*)&shf[k4 << 2];
            float a[4];
            a[0] = fmaxf(fmaf(hv.x, sc.x, sh.x), 0.f);
            a[1] = fmaxf(fmaf(hv.y, sc.y, sh.y), 0.f);
            a[2] = fmaxf(fmaf(hv.z, sc.z, sh.z), 0.f);
            a[3] = fmaxf(fmaf(hv.w, sc.w, sh.w), 0.f);
#pragma unroll
            for (int e = 0; e < 4; ++e) {
                const int k = (k4 << 2) + e;
                const float4 wa = *(const float4*)&Ws2[k * 32 + (cg << 3)];
                const float4 wb = *(const float4*)&Ws2[k * 32 + (cg << 3) + 4];
                z[0] = fmaf(a[e], wa.x, z[0]); z[1] = fmaf(a[e], wa.y, z[1]);
                z[2] = fmaf(a[e], wa.z, z[2]); z[3] = fmaf(a[e], wa.w, z[3]);
                z[4] = fmaf(a[e], wb.x, z[4]); z[5] = fmaf(a[e], wb.y, z[5]);
                z[6] = fmaf(a[e], wb.z, z[6]); z[7] = fmaf(a[e], wb.w, z[7]);
            }
        }
        z[0] += bza.x; z[1] += bza.y; z[2] += bza.z; z[3] += bza.w;
        z[4] += bzb.x; z[5] += bzb.y; z[6] += bzb.z; z[7] += bzb.w;
        float pn = 0.f;
#pragma unroll
        for (int j = 0; j < 8; ++j) {
            zf[row * 33 + (cg << 3) + j] = z[j];
            pn = fmaf(z[j], z[j], pn);
        }
        *(uint4*)&zs[row * 40 + (cg << 3)] =
            make_uint4(pack2(z[0], z[1]), pack2(z[2], z[3]),
                       pack2(z[4], z[5]), pack2(z[6], z[7]));
        pn += __shfl_xor(pn, 1);
        pn += __shfl_xor(pn, 2);
        if (cg == 0) zn[row] = pn;
    }
    __syncthreads();

    // --- Phase B: quant sweep (bf16 proxy for argmin only) ---
    bf8 af[2];
    af[0] = *(const bf8*)&zs[(w * 32 + lcol) * 40 + (quad << 3)];
    af[1] = *(const bf8*)&zs[(w * 32 + 16 + lcol) * 40 + (quad << 3)];
    float best[2][4];
    int bidx[2][4];
#pragma unroll
    for (int mt = 0; mt < 2; ++mt)
#pragma unroll
        for (int r = 0; r < 4; ++r) { best[mt][r] = 3.4e38f; bidx[mt][r] = 0; }
    const f4a zero4 = {0.f, 0.f, 0.f, 0.f};

    for (int cp = 0; cp < 4; ++cp) {
        __syncthreads();
#pragma unroll
        for (int i = 0; i < 4; ++i) {   // b128 copy of prepped bf16 codebook
            int idx = (i << 8) + t;
            int r = idx >> 2, kq = (idx & 3) << 3;
            *(uint4*)&cs[r * 40 + kq] = *(const uint4*)(cbb + (size_t)((cp << 8) + r) * 32 + kq);
        }
        cn[t] = cn_g[(cp << 8) + t];
        __syncthreads();
        bf8 bb = *(const bf8*)&cs[lcol * 40 + (quad << 3)];
        float cnv = cn[lcol];
        for (int ch = 0; ch < 16; ++ch) {
            const int nn = ((ch + 1) & 15) << 4;
            const bf8 bb_n = *(const bf8*)&cs[(nn + lcol) * 40 + (quad << 3)];
            const float cn_n = cn[nn + lcol];
            const int cidx = (cp << 8) + (ch << 4) + lcol;
#pragma unroll
            for (int mt = 0; mt < 2; ++mt) {
                f4a a = __builtin_amdgcn_mfma_f32_16x16x32_bf16(af[mt], bb, zero4, 0, 0, 0);
#pragma unroll
                for (int r = 0; r < 4; ++r) {
                    float d = fmaf(-2.f, a[r], cnv);   // proxy: cn - 2 z.c (zn const per row)
                    if (d < best[mt][r]) { best[mt][r] = d; bidx[mt][r] = cidx; }
                }
            }
            bb = bb_n; cnv = cn_n;
        }
    }
    // cross-lane argmin (first-index tie-break) -> all 16 lanes of each group converge
#pragma unroll
    for (int off = 1; off < 16; off <<= 1) {
#pragma unroll
        for (int mt = 0; mt < 2; ++mt)
#pragma unroll
            for (int r = 0; r < 4; ++r) {
                float ob = __shfl_xor(best[mt][r], off);
                int oi = __shfl_xor(bidx[mt][r], off);
                if (ob < best[mt][r] || (ob == best[mt][r] && oi < bidx[mt][r])) {
                    best[mt][r] = ob; bidx[mt][r] = oi;
                }
            }
    }
    // exact fp32 distance of the selected codeword (fp32 z from zf, fp32 cb)
    float lsum = 0.f;
#pragma unroll
    for (int mt = 0; mt < 2; ++mt) {
#pragma unroll
        for (int r = 0; r < 4; ++r) {
            const int rowl = w * 32 + mt * 16 + (quad << 2) + r;
            const int ti = bidx[mt][r];
            const float* cp_ = cb + (size_t)ti * 32;
            float d0 = zf[rowl * 33 + lcol] - cp_[lcol];
            float d1 = zf[rowl * 33 + 16 + lcol] - cp_[16 + lcol];
            float p = fmaf(d0, d0, d1 * d1);
            p += __shfl_xor(p, 1); p += __shfl_xor(p, 2);
            p += __shfl_xor(p, 4); p += __shfl_xor(p, 8);
            if (lcol == 0) {
                topicsL[rowl] = ti;
                lsum += p;
            }
        }
    }
    red[t] = lsum;
    __syncthreads();
    for (int s = 128; s > 0; s >>= 1) {
        if (t < s) red[t] += red[t + s];
        __syncthreads();
    }
    if (t == 0) atomicAdd(acc_g + 512, red[0]);
    // (final __syncthreads of reduce loop: zf/cs reads done -> regions 0/1 reusable)

    // --- Phase C: dec1 via bf16 MFMA; h2b bf16 store + stats2 ---
    // stage W1dT[n][k] bf16 (w1d: [32][128], pack pairs along k)
#pragma unroll
    for (int i = 0; i < 8; ++i) {
        int idx = (i << 8) + t;
        int n = idx & 127, kp = idx >> 7;   // kp 0..15
        unsigned v = pack2(w1d[(size_t)(2 * kp) * 128 + n],
                           w1d[(size_t)(2 * kp + 1) * 128 + n]);
        *(unsigned*)&W1dT[n * 40 + (kp << 1)] = v;
    }
    // gather selected codewords bf16 (b128 copies from cbb)
#pragma unroll
    for (int i = 0; i < 2; ++i) {
        int idx = (i << 8) + t;
        int r = idx >> 2, p = idx & 3;
        *(uint4*)&Qs[r * 40 + (p << 3)] =
            *(const uint4*)(cbb + (size_t)topicsL[r] * 32 + (p << 3));
    }
    __syncthreads();
    f4a dacc[2][8];
#pragma unroll
    for (int i = 0; i < 2; ++i)
#pragma unroll
        for (int j = 0; j < 8; ++j) dacc[i][j] = (f4a){0.f, 0.f, 0.f, 0.f};
    const bf8 da0 = *(const bf8*)&Qs[(w * 32 + lcol) * 40 + (quad << 3)];
    const bf8 da1 = *(const bf8*)&Qs[(w * 32 + 16 + lcol) * 40 + (quad << 3)];
#pragma unroll
    for (int nt = 0; nt < 8; ++nt) {
        const bf8 bb = *(const bf8*)&W1dT[(nt * 16 + lcol) * 40 + (quad << 3)];
        dacc[0][nt] = __builtin_amdgcn_mfma_f32_16x16x32_bf16(da0, bb, dacc[0][nt], 0, 0, 0);
        dacc[1][nt] = __builtin_amdgcn_mfma_f32_16x16x32_bf16(da1, bb, dacc[1][nt], 0, 0, 0);
    }
    // epilogue: bf16 h2 store + stats2 (sstat2 disjoint from W1dT/Qs -> no barrier needed)
#pragma unroll
    for (int nt = 0; nt < 8; ++nt) {
        const int gc = (nt << 4) + lcol;
        const float bias = b1d[gc];
        float s = 0.f, ss = 0.f;
#pragma unroll
        for (int mt = 0; mt < 2; ++mt) {
            const int rbase = row0 + w * 32 + mt * 16 + (quad << 2);
#pragma unroll
            for (int r = 0; r < 4; ++r) {
                float v = dacc[mt][nt][r] + bias;
                h2b[(size_t)(rbase + r) * 128 + gc] = f2bf(v);
                s += v;
                ss = fmaf(v, v, ss);
            }
        }
        s += __shfl_xor(s, 16);  s += __shfl_xor(s, 32);
        ss += __shfl_xor(ss, 16); ss += __shfl_xor(ss, 32);
        if (quad == 0) { sstat2[w * 128 + gc] = s; sstat2[512 + w * 128 + gc] = ss; }
    }
    __syncthreads();
    if (t < 128) {
        atomicAdd(&acc_g[256 + t], sstat2[t] + sstat2[128 + t] + sstat2[256 + t] + sstat2[384 + t]);
        atomicAdd(&acc_g[384 + t], sstat2[512 + t] + sstat2[640 + t] + sstat2[768 + t] + sstat2[896 + t]);
    }
}

// ======== K3: X_ = relu(bn(h2b))@dw2 + db2 ; accumulate sum((X_-X)^2) ========
// 512 thr (8 waves, 2x4), tile 128M x 256N, BK=32 (4 chunks), grid (512, 2).
__global__ __launch_bounds__(512) void k_dec2(const unsigned short* __restrict__ h2b,
                                              float* acc_g,
                                              const float* __restrict__ g,
                                              const float* __restrict__ be,
                                              const float* __restrict__ w2,
                                              const float* __restrict__ b2,
                                              const float* __restrict__ X) {
    __shared__ unsigned short As[128 * 40];
    __shared__ unsigned short Bs[256 * 40];
    __shared__ float scl[128], shf[128];
    __shared__ float red[512];
    const int t = threadIdx.x;
    if (t < 128) {
        float mu = acc_g[256 + t] * (1.f / 65536.f);
        float var = fmaf(-mu, mu, acc_g[384 + t] * (1.f / 65536.f));
        float s = g[t] * rsqrtf(var + 1e-5f);
        scl[t] = s;
        shf[t] = fmaf(-mu, s, be[t]);
    }
    const int row0 = blockIdx.x << 7;
    const int col0 = blockIdx.y << 8;
    const int w = t >> 6, lane = t & 63, quad = lane >> 4, lcol = lane & 15;
    const int wm = w & 1, wn = w >> 1;
    f4a acc[4][4];
#pragma unroll
    for (int i = 0; i < 4; i++)
#pragma unroll
        for (int j = 0; j < 4; j++) acc[i][j] = (f4a){0.f, 0.f, 0.f, 0.f};
    __syncthreads();

    const int bn = t & 255, bkg = t >> 8;
    const int ar = t >> 2, akq = (t & 3) << 3;
    for (int c = 0; c < 4; ++c) {
        const int k0 = c << 5;
        if (c) __syncthreads();
        // A: bf16 h2 tile, BN+ReLU fused (one uint4 = 8 bf16 per thread per chunk)
        {
            uint4 raw = *(const uint4*)(h2b + (size_t)(row0 + ar) * 128 + k0 + akq);
            unsigned pv[4] = {raw.x, raw.y, raw.z, raw.w};
            unsigned ov[4];
#pragma unroll
            for (int j = 0; j < 4; ++j) {
                float lo, hi;
                unpack2(pv[j], lo, hi);
                int k = k0 + akq + 2 * j;
                lo = fmaxf(fmaf(lo, scl[k], shf[k]), 0.f);
                hi = fmaxf(fmaf(hi, scl[k + 1], shf[k + 1]), 0.f);
                ov[j] = pack2(lo, hi);
            }
            *(uint4*)&As[ar * 40 + akq] = make_uint4(ov[0], ov[1], ov[2], ov[3]);
        }
        // B: w2 chunk [32k][256n] -> Bs[n][k]
#pragma unroll
        for (int i = 0; i < 4; ++i) {
            int k = (bkg << 4) + (i << 2);
            const float* p = w2 + (size_t)(k0 + k) * 512 + col0 + bn;
            float a0 = p[0], a1 = p[512], a2 = p[1024], a3 = p[1536];
            *(uint2*)&Bs[bn * 40 + k] = make_uint2(pack2(a0, a1), pack2(a2, a3));
        }
        __syncthreads();
        bf8 af[4];
#pragma unroll
        for (int mt = 0; mt < 4; ++mt)
            af[mt] = *(const bf8*)&As[(wm * 64 + mt * 16 + lcol) * 40 + (quad << 3)];
#pragma unroll
        for (int nt = 0; nt < 4; ++nt) {
            const bf8 bb = *(const bf8*)&Bs[(wn * 64 + nt * 16 + lcol) * 40 + (quad << 3)];
#pragma unroll
            for (int mt = 0; mt < 4; ++mt)
                acc[mt][nt] = __builtin_amdgcn_mfma_f32_16x16x32_bf16(af[mt], bb, acc[mt][nt], 0, 0, 0);
        }
    }
    float lsum = 0.f;
#pragma unroll
    for (int nt = 0; nt < 4; ++nt) {
        const int gc = col0 + wn * 64 + nt * 16 + lcol;
        const float bias = b2[gc];
#pragma unroll
        for (int mt = 0; mt < 4; ++mt) {
            const int rbase = row0 + wm * 64 + mt * 16 + (quad << 2);
#pragma unroll
            for (int r = 0; r < 4; ++r) {
                float val = acc[mt][nt][r] + bias;
                float d = val - X[(size_t)(rbase + r) * 512 + gc];
                lsum = fmaf(d, d, lsum);
            }
        }
    }
    red[t] = lsum;
    __syncthreads();
    for (int s = 256; s > 0; s >>= 1) {
        if (t < s) red[t] += red[t + s];
        __syncthreads();
    }
    if (t == 0) atomicAdd(acc_g + 513, red[0]);
}

__global__ void k_final(const float* __restrict__ acc, float* __restrict__ out) {
    if (threadIdx.x == 0) out[0] = 2.f * acc[512] + sqrtf(acc[513]);
}

extern "C" void kernel_launch(void* const* d_in, const int* in_sizes, int n_in,
                              void* d_out, int out_size, void* d_ws, size_t ws_size,
                              hipStream_t stream) {
    const float* X       = (const float*)d_in[0];
    const float* enc_w1  = (const float*)d_in[1];
    const float* enc_b1  = (const float*)d_in[2];
    const float* enc_g1  = (const float*)d_in[3];
    const float* enc_be1 = (const float*)d_in[4];
    const float* enc_w2  = (const float*)d_in[5];
    const float* enc_b2  = (const float*)d_in[6];
    const float* dec_w1  = (const float*)d_in[7];
    const float* dec_b1  = (const float*)d_in[8];
    const float* dec_g1  = (const float*)d_in[9];
    const float* dec_be1 = (const float*)d_in[10];
    const float* dec_w2  = (const float*)d_in[11];
    const float* dec_b2  = (const float*)d_in[12];
    const float* cb      = (const float*)d_in[13];
    float* out = (float*)d_out;

    float* acc = (float*)d_ws;                               // 1024 f32
    unsigned short* cbb = (unsigned short*)(acc + 1024);     // 1024*32 bf16
    float* cn_g = (float*)(cbb + 1024 * 32);                 // 1024 f32
    float* h1 = cn_g + 1024;                                 // 65536*128 f32
    unsigned short* h2b = (unsigned short*)(h1 + (size_t)65536 * 128);  // bf16

    k_prep<<<5, 256, 0, stream>>>(cb, acc, cbb, cn_g);
    k_enc1<<<512, 256, 0, stream>>>(X, enc_w1, enc_b1, h1, acc);
    k_mid<<<512, 256, 0, stream>>>(h1, enc_w2, enc_b2, enc_g1, enc_be1,
                                   cb, cbb, cn_g, dec_w1, dec_b1, h2b, acc);
    k_dec2<<<dim3(512, 2), 512, 0, stream>>>(h2b, acc, dec_g1, dec_be1, dec_w2, dec_b2, X);
    k_final<<<1, 64, 0, stream>>>(acc, out);
}

// Round 7
// 314.492 us; speedup vs baseline: 1.0461x; 1.0295x over previous
//
#include <hip/hip_runtime.h>
#include <math.h>

// VQ-AE forward. z-path accuracy-critical (output ~2.5e6 = 2*z_loss; check is
// ~bf16-ULP at that magnitude): h1 fp32, z via SPLIT-bf16 MFMA (a_hi+a_lo,
// w_hi+w_lo; 3 products -> ~2^-18 per-term error), exact fp32 selected-distance.
// Post-topics path (dec1, h2, dec2) single bf16 (enters only via sqrt-term ~5.8e3).
// ws: acc[1024] f32 | cbb[1024*32] bf16 | cn_g[1024] f32 | h1[65536*128] f32 | h2b[...] bf16
// acc: [0..127] sum1, [128..255] sumsq1, [256..383] sum2, [384..511] sumsq2,
//      [512] min-dist sum, [513] sq-diff sum

typedef __attribute__((ext_vector_type(8))) short bf8;
typedef __attribute__((ext_vector_type(4))) float f4a;

__device__ __forceinline__ unsigned short f2bf(float f) {
    unsigned u = __float_as_uint(f);
    u += 0x7fffu + ((u >> 16) & 1u);   // RNE
    return (unsigned short)(u >> 16);
}
__device__ __forceinline__ float bf2f(unsigned short h) {
    return __uint_as_float((unsigned)h << 16);
}
__device__ __forceinline__ unsigned pack2(float a, float b) {
    return (unsigned)f2bf(a) | ((unsigned)f2bf(b) << 16);
}
__device__ __forceinline__ void unpack2(unsigned p, float& lo, float& hi) {
    lo = __uint_as_float(p << 16);
    hi = __uint_as_float(p & 0xffff0000u);
}

// ======== K0: zero acc + codebook -> bf16 + fp32 norms ========
__global__ __launch_bounds__(256) void k_prep(const float* __restrict__ cb,
                                              float* __restrict__ acc,
                                              unsigned short* __restrict__ cbb,
                                              float* __restrict__ cn_g) {
    const int b = blockIdx.x, t = threadIdx.x;
    if (b < 4) {
        const int cw = (b << 8) + t;
        const float* p = cb + (size_t)cw * 32;
        unsigned out[16];
        float n = 0.f;
#pragma unroll
        for (int i = 0; i < 8; ++i) {
            float4 v = *(const float4*)(p + (i << 2));
            n = fmaf(v.x, v.x, n); n = fmaf(v.y, v.y, n);
            n = fmaf(v.z, v.z, n); n = fmaf(v.w, v.w, n);
            out[2 * i]     = pack2(v.x, v.y);
            out[2 * i + 1] = pack2(v.z, v.w);
        }
#pragma unroll
        for (int i = 0; i < 4; ++i)
            *(uint4*)(cbb + (size_t)cw * 32 + (i << 3)) =
                make_uint4(out[4 * i], out[4 * i + 1], out[4 * i + 2], out[4 * i + 3]);
        cn_g[cw] = n;
    } else {
        for (int i = t; i < 1024; i += 256) acc[i] = 0.f;
    }
}

// ======== K1: h1 = fp32(X@w1 + b1) (bf16 MFMA), + column sum/sumsq ========
__global__ __launch_bounds__(256) void k_enc1(const float* __restrict__ X,
                                              const float* __restrict__ w1,
                                              const float* __restrict__ b1,
                                              float* __restrict__ h1,
                                              float* __restrict__ acc_g) {
    __shared__ unsigned short As[128 * 72];
    __shared__ unsigned short Bs[128 * 72];
    __shared__ float sred[2 * 4 * 128];   // [stat][wave][col]
    const int t = threadIdx.x;
    const int row0 = blockIdx.x << 7;
    const int w = t >> 6, lane = t & 63, quad = lane >> 4, lcol = lane & 15;
    f4a acc[2][8];
#pragma unroll
    for (int i = 0; i < 2; i++)
#pragma unroll
        for (int j = 0; j < 8; j++) acc[i][j] = (f4a){0.f, 0.f, 0.f, 0.f};

    const int bn = t & 127, bkg = t >> 7;
    for (int c = 0; c < 8; ++c) {
        const int k0 = c << 6;
        __syncthreads();
#pragma unroll
        for (int i = 0; i < 8; ++i) {
            int fidx = (i << 8) + t;
            int r = fidx >> 4, kq = (fidx & 15) << 2;
            float4 v = *(const float4*)(X + (size_t)(row0 + r) * 512 + k0 + kq);
            *(uint2*)&As[r * 72 + kq] = make_uint2(pack2(v.x, v.y), pack2(v.z, v.w));
        }
#pragma unroll
        for (int i = 0; i < 8; ++i) {
            int k = (bkg << 5) + (i << 2);
            const float* p = w1 + (size_t)(k0 + k) * 128 + bn;
            float a0 = p[0], a1 = p[128], a2 = p[256], a3 = p[384];
            *(uint2*)&Bs[bn * 72 + k] = make_uint2(pack2(a0, a1), pack2(a2, a3));
        }
        __syncthreads();
#pragma unroll
        for (int ks = 0; ks < 2; ++ks) {
            const bf8 a0 = *(const bf8*)&As[(w * 32 + lcol) * 72 + (ks << 5) + (quad << 3)];
            const bf8 a1 = *(const bf8*)&As[(w * 32 + 16 + lcol) * 72 + (ks << 5) + (quad << 3)];
#pragma unroll
            for (int nt = 0; nt < 8; ++nt) {
                const bf8 bb = *(const bf8*)&Bs[(nt * 16 + lcol) * 72 + (ks << 5) + (quad << 3)];
                acc[0][nt] = __builtin_amdgcn_mfma_f32_16x16x32_bf16(a0, bb, acc[0][nt], 0, 0, 0);
                acc[1][nt] = __builtin_amdgcn_mfma_f32_16x16x32_bf16(a1, bb, acc[1][nt], 0, 0, 0);
            }
        }
    }
#pragma unroll
    for (int nt = 0; nt < 8; ++nt) {
        const int gc = (nt << 4) + lcol;
        const float bias = b1[gc];
        float s = 0.f, ss = 0.f;
#pragma unroll
        for (int mt = 0; mt < 2; ++mt) {
            const int rbase = row0 + w * 32 + mt * 16 + (quad << 2);
#pragma unroll
            for (int r = 0; r < 4; ++r) {
                float v = acc[mt][nt][r] + bias;
                h1[(size_t)(rbase + r) * 128 + gc] = v;
                s += v;
                ss = fmaf(v, v, ss);
            }
        }
        s += __shfl_xor(s, 16);  s += __shfl_xor(s, 32);
        ss += __shfl_xor(ss, 16); ss += __shfl_xor(ss, 32);
        if (quad == 0) { sred[w * 128 + gc] = s; sred[512 + w * 128 + gc] = ss; }
    }
    __syncthreads();
    if (t < 128) {
        atomicAdd(&acc_g[t], sred[t] + sred[128 + t] + sred[256 + t] + sred[384 + t]);
        atomicAdd(&acc_g[128 + t], sred[512 + t] + sred[640 + t] + sred[768 + t] + sred[896 + t]);
    }
}

// ======== K2: fused enc2(split-bf16 MFMA) + quantize(bf16 argmin, fp32 dist) + dec1(bf16 MFMA) ========
// 512 blocks x 256 thr, 128 rows/block.
__global__ __launch_bounds__(256) void k_mid(const float* __restrict__ h1,
                                             const float* __restrict__ w2e,
                                             const float* __restrict__ b2e,
                                             const float* __restrict__ g1,
                                             const float* __restrict__ be1,
                                             const float* __restrict__ cb,
                                             const unsigned short* __restrict__ cbb,
                                             const float* __restrict__ cn_g,
                                             const float* __restrict__ w1d,
                                             const float* __restrict__ b1d,
                                             unsigned short* __restrict__ h2b,
                                             float* __restrict__ acc_g) {
    // LDS pool (58880 B), phase-sequenced:
    //  region0 @0 (46080): Phase A: Ash[0,18432) Asl[18432,36864) Bs2h[36864,41472) Bs2l[41472,46080)
    //                      Phase B: cs us[256*40] [0,20480) + cn f32[256] [20480,21504)
    //                      Phase C: W1dT us[128*40] [0,10240) + Qs us[128*40] [10240,20480)
    //                               + sstat2 f32[1024] [20480,24576)
    //  zs   @46080 (10240): bf16 z, A-layout (A -> B frags)
    //  red  @56320 (1024) | topicsL @57344 (512) | scl @57856 (512) | shf @58368 (512)
    __shared__ __align__(16) char pool[58880];
    unsigned short* Ash  = (unsigned short*)pool;
    unsigned short* Asl  = (unsigned short*)(pool + 18432);
    unsigned short* Bs2h = (unsigned short*)(pool + 36864);
    unsigned short* Bs2l = (unsigned short*)(pool + 41472);
    unsigned short* cs   = (unsigned short*)pool;
    float*          cn   = (float*)(pool + 20480);
    unsigned short* W1dT = (unsigned short*)pool;
    unsigned short* Qs   = (unsigned short*)(pool + 10240);
    float*          sstat2 = (float*)(pool + 20480);
    unsigned short* zs   = (unsigned short*)(pool + 46080);
    float* red   = (float*)(pool + 56320);
    int*   topicsL = (int*)(pool + 57344);
    float* scl   = (float*)(pool + 57856);
    float* shf   = (float*)(pool + 58368);

    const int t = threadIdx.x;
    const int w = t >> 6, lane = t & 63, quad = lane >> 4, lcol = lane & 15;
    const int row0 = blockIdx.x << 7;

    // --- BN params (enc) + stage w2e hi/lo splits (Bs2[n][k], stride 72) ---
    if (t < 128) {
        float mu = acc_g[t] * (1.f / 65536.f);
        float var = fmaf(-mu, mu, acc_g[128 + t] * (1.f / 65536.f));
        float s = g1[t] * rsqrtf(var + 1e-5f);
        scl[t] = s;
        shf[t] = fmaf(-mu, s, be1[t]);
    }
#pragma unroll
    for (int i = 0; i < 16; ++i) {
        int idx = (i << 8) + t;
        int n = idx & 31, k = idx >> 5;
        float f = w2e[k * 32 + n];
        unsigned short hi = f2bf(f);
        Bs2h[n * 72 + k] = hi;
        Bs2l[n * 72 + k] = f2bf(f - bf2f(hi));
    }
    __syncthreads();

    // --- Phase A stage: As_hi/As_lo = split(bn_relu(h1 tile)) [128m][128k] stride 72 ---
    {
        const int kq = (t & 15) << 3;   // constant per thread across iters
        const int rb = t >> 4;
        const float4 sc0 = *(const float4*)&scl[kq];
        const float4 sc1 = *(const float4*)&scl[kq + 4];
        const float4 sh0 = *(const float4*)&shf[kq];
        const float4 sh1 = *(const float4*)&shf[kq + 4];
#pragma unroll
        for (int i = 0; i < 8; ++i) {
            const int r = (i << 4) + rb;
            const float* hp = h1 + (size_t)(row0 + r) * 128 + kq;
            float4 v0 = *(const float4*)hp;
            float4 v1 = *(const float4*)(hp + 4);
            float a[8];
            a[0] = fmaxf(fmaf(v0.x, sc0.x, sh0.x), 0.f);
            a[1] = fmaxf(fmaf(v0.y, sc0.y, sh0.y), 0.f);
            a[2] = fmaxf(fmaf(v0.z, sc0.z, sh0.z), 0.f);
            a[3] = fmaxf(fmaf(v0.w, sc0.w, sh0.w), 0.f);
            a[4] = fmaxf(fmaf(v1.x, sc1.x, sh1.x), 0.f);
            a[5] = fmaxf(fmaf(v1.y, sc1.y, sh1.y), 0.f);
            a[6] = fmaxf(fmaf(v1.z, sc1.z, sh1.z), 0.f);
            a[7] = fmaxf(fmaf(v1.w, sc1.w, sh1.w), 0.f);
            unsigned hiw[4], low[4];
#pragma unroll
            for (int j = 0; j < 4; ++j) {
                float x0 = a[2 * j], x1 = a[2 * j + 1];
                unsigned short h0 = f2bf(x0), h1u = f2bf(x1);
                float r0 = x0 - bf2f(h0), r1 = x1 - bf2f(h1u);
                hiw[j] = (unsigned)h0 | ((unsigned)h1u << 16);
                low[j] = (unsigned)f2bf(r0) | ((unsigned)f2bf(r1) << 16);
            }
            *(uint4*)&Ash[r * 72 + kq] = make_uint4(hiw[0], hiw[1], hiw[2], hiw[3]);
            *(uint4*)&Asl[r * 72 + kq] = make_uint4(low[0], low[1], low[2], low[3]);
        }
    }
    __syncthreads();

    // --- Phase A compute: z = a@w2e + b2e via 3-product split-bf16 MFMA ---
    f4a zacc[2][2];
#pragma unroll
    for (int i = 0; i < 2; ++i)
#pragma unroll
        for (int j = 0; j < 2; ++j) zacc[i][j] = (f4a){0.f, 0.f, 0.f, 0.f};
#pragma unroll
    for (int kc = 0; kc < 4; ++kc) {
        const int ko = (kc << 5) + (quad << 3);
        const bf8 ah0 = *(const bf8*)&Ash[(w * 32 + lcol) * 72 + ko];
        const bf8 ah1 = *(const bf8*)&Ash[(w * 32 + 16 + lcol) * 72 + ko];
        const bf8 al0 = *(const bf8*)&Asl[(w * 32 + lcol) * 72 + ko];
        const bf8 al1 = *(const bf8*)&Asl[(w * 32 + 16 + lcol) * 72 + ko];
        const bf8 bh0 = *(const bf8*)&Bs2h[lcol * 72 + ko];
        const bf8 bh1 = *(const bf8*)&Bs2h[(16 + lcol) * 72 + ko];
        const bf8 bl0 = *(const bf8*)&Bs2l[lcol * 72 + ko];
        const bf8 bl1 = *(const bf8*)&Bs2l[(16 + lcol) * 72 + ko];
        zacc[0][0] = __builtin_amdgcn_mfma_f32_16x16x32_bf16(ah0, bh0, zacc[0][0], 0, 0, 0);
        zacc[0][0] = __builtin_amdgcn_mfma_f32_16x16x32_bf16(al0, bh0, zacc[0][0], 0, 0, 0);
        zacc[0][0] = __builtin_amdgcn_mfma_f32_16x16x32_bf16(ah0, bl0, zacc[0][0], 0, 0, 0);
        zacc[0][1] = __builtin_amdgcn_mfma_f32_16x16x32_bf16(ah0, bh1, zacc[0][1], 0, 0, 0);
        zacc[0][1] = __builtin_amdgcn_mfma_f32_16x16x32_bf16(al0, bh1, zacc[0][1], 0, 0, 0);
        zacc[0][1] = __builtin_amdgcn_mfma_f32_16x16x32_bf16(ah0, bl1, zacc[0][1], 0, 0, 0);
        zacc[1][0] = __builtin_amdgcn_mfma_f32_16x16x32_bf16(ah1, bh0, zacc[1][0], 0, 0, 0);
        zacc[1][0] = __builtin_amdgcn_mfma_f32_16x16x32_bf16(al1, bh0, zacc[1][0], 0, 0, 0);
        zacc[1][0] = __builtin_amdgcn_mfma_f32_16x16x32_bf16(ah1, bl0, zacc[1][0], 0, 0, 0);
        zacc[1][1] = __builtin_amdgcn_mfma_f32_16x16x32_bf16(ah1, bh1, zacc[1][1], 0, 0, 0);
        zacc[1][1] = __builtin_amdgcn_mfma_f32_16x16x32_bf16(al1, bh1, zacc[1][1], 0, 0, 0);
        zacc[1][1] = __builtin_amdgcn_mfma_f32_16x16x32_bf16(ah1, bl1, zacc[1][1], 0, 0, 0);
    }
    // bias; keep fp32 z in regs (C-layout matches sweep layout); bf16 z -> zs (A-layout)
    const float b2lo = b2e[lcol], b2hi = b2e[16 + lcol];
    float zf0[2][4], zf1[2][4];
#pragma unroll
    for (int mt = 0; mt < 2; ++mt) {
#pragma unroll
        for (int r = 0; r < 4; ++r) {
            float v0 = zacc[mt][0][r] + b2lo;
            float v1 = zacc[mt][1][r] + b2hi;
            zf0[mt][r] = v0;
            zf1[mt][r] = v1;
            int row = w * 32 + mt * 16 + (quad << 2) + r;
            zs[row * 40 + lcol] = f2bf(v0);
            zs[row * 40 + 16 + lcol] = f2bf(v1);
        }
    }
    __syncthreads();   // zs complete; Ash/Asl/Bs2 dead -> region0 reusable

    // --- Phase B: quant sweep (bf16 proxy for argmin only) ---
    bf8 af[2];
    af[0] = *(const bf8*)&zs[(w * 32 + lcol) * 40 + (quad << 3)];
    af[1] = *(const bf8*)&zs[(w * 32 + 16 + lcol) * 40 + (quad << 3)];
    float best[2][4];
    int bidx[2][4];
#pragma unroll
    for (int mt = 0; mt < 2; ++mt)
#pragma unroll
        for (int r = 0; r < 4; ++r) { best[mt][r] = 3.4e38f; bidx[mt][r] = 0; }
    const f4a zero4 = {0.f, 0.f, 0.f, 0.f};

    for (int cp = 0; cp < 4; ++cp) {
        if (cp) __syncthreads();
#pragma unroll
        for (int i = 0; i < 4; ++i) {   // b128 copy of prepped bf16 codebook
            int idx = (i << 8) + t;
            int r = idx >> 2, kq = (idx & 3) << 3;
            *(uint4*)&cs[r * 40 + kq] = *(const uint4*)(cbb + (size_t)((cp << 8) + r) * 32 + kq);
        }
        cn[t] = cn_g[(cp << 8) + t];
        __syncthreads();
        bf8 bb = *(const bf8*)&cs[lcol * 40 + (quad << 3)];
        float cnv = cn[lcol];
        for (int ch = 0; ch < 16; ++ch) {
            const int nn = ((ch + 1) & 15) << 4;
            const bf8 bb_n = *(const bf8*)&cs[(nn + lcol) * 40 + (quad << 3)];
            const float cn_n = cn[nn + lcol];
            const int cidx = (cp << 8) + (ch << 4) + lcol;
#pragma unroll
            for (int mt = 0; mt < 2; ++mt) {
                f4a a = __builtin_amdgcn_mfma_f32_16x16x32_bf16(af[mt], bb, zero4, 0, 0, 0);
#pragma unroll
                for (int r = 0; r < 4; ++r) {
                    float d = fmaf(-2.f, a[r], cnv);   // proxy: cn - 2 z.c (zn const per row)
                    if (d < best[mt][r]) { best[mt][r] = d; bidx[mt][r] = cidx; }
                }
            }
            bb = bb_n; cnv = cn_n;
        }
    }
    // cross-lane argmin (first-index tie-break) -> all 16 lanes of each group converge
#pragma unroll
    for (int off = 1; off < 16; off <<= 1) {
#pragma unroll
        for (int mt = 0; mt < 2; ++mt)
#pragma unroll
            for (int r = 0; r < 4; ++r) {
                float ob = __shfl_xor(best[mt][r], off);
                int oi = __shfl_xor(bidx[mt][r], off);
                if (ob < best[mt][r] || (ob == best[mt][r] && oi < bidx[mt][r])) {
                    best[mt][r] = ob; bidx[mt][r] = oi;
                }
            }
    }
    // exact fp32 distance of the selected codeword (register z, fp32 cb)
    float lsum = 0.f;
#pragma unroll
    for (int mt = 0; mt < 2; ++mt) {
#pragma unroll
        for (int r = 0; r < 4; ++r) {
            const int rowl = w * 32 + mt * 16 + (quad << 2) + r;
            const int ti = bidx[mt][r];
            const float* cp_ = cb + (size_t)ti * 32;
            float d0 = zf0[mt][r] - cp_[lcol];
            float d1 = zf1[mt][r] - cp_[16 + lcol];
            float p = fmaf(d0, d0, d1 * d1);
            p += __shfl_xor(p, 1); p += __shfl_xor(p, 2);
            p += __shfl_xor(p, 4); p += __shfl_xor(p, 8);
            if (lcol == 0) {
                topicsL[rowl] = ti;
                lsum += p;
            }
        }
    }
    red[t] = lsum;
    __syncthreads();
    for (int s = 128; s > 0; s >>= 1) {
        if (t < s) red[t] += red[t + s];
        __syncthreads();
    }
    if (t == 0) atomicAdd(acc_g + 512, red[0]);
    // (final __syncthreads of reduce loop: cs/sweep reads done -> region0 reusable)

    // --- Phase C: dec1 via bf16 MFMA; h2b bf16 store + stats2 ---
#pragma unroll
    for (int i = 0; i < 8; ++i) {   // W1dT[n][k] bf16 (w1d: [32][128])
        int idx = (i << 8) + t;
        int n = idx & 127, kp = idx >> 7;   // kp 0..15
        unsigned v = pack2(w1d[(size_t)(2 * kp) * 128 + n],
                           w1d[(size_t)(2 * kp + 1) * 128 + n]);
        *(unsigned*)&W1dT[n * 40 + (kp << 1)] = v;
    }
#pragma unroll
    for (int i = 0; i < 2; ++i) {   // gather selected codewords (b128 from cbb)
        int idx = (i << 8) + t;
        int r = idx >> 2, p = idx & 3;
        *(uint4*)&Qs[r * 40 + (p << 3)] =
            *(const uint4*)(cbb + (size_t)topicsL[r] * 32 + (p << 3));
    }
    __syncthreads();
    f4a dacc[2][8];
#pragma unroll
    for (int i = 0; i < 2; ++i)
#pragma unroll
        for (int j = 0; j < 8; ++j) dacc[i][j] = (f4a){0.f, 0.f, 0.f, 0.f};
    const bf8 da0 = *(const bf8*)&Qs[(w * 32 + lcol) * 40 + (quad << 3)];
    const bf8 da1 = *(const bf8*)&Qs[(w * 32 + 16 + lcol) * 40 + (quad << 3)];
#pragma unroll
    for (int nt = 0; nt < 8; ++nt) {
        const bf8 bb = *(const bf8*)&W1dT[(nt * 16 + lcol) * 40 + (quad << 3)];
        dacc[0][nt] = __builtin_amdgcn_mfma_f32_16x16x32_bf16(da0, bb, dacc[0][nt], 0, 0, 0);
        dacc[1][nt] = __builtin_amdgcn_mfma_f32_16x16x32_bf16(da1, bb, dacc[1][nt], 0, 0, 0);
    }
    // epilogue: bf16 h2 store + stats2 (sstat2 disjoint from W1dT/Qs)
#pragma unroll
    for (int nt = 0; nt < 8; ++nt) {
        const int gc = (nt << 4) + lcol;
        const float bias = b1d[gc];
        float s = 0.f, ss = 0.f;
#pragma unroll
        for (int mt = 0; mt < 2; ++mt) {
            const int rbase = row0 + w * 32 + mt * 16 + (quad << 2);
#pragma unroll
            for (int r = 0; r < 4; ++r) {
                float v = dacc[mt][nt][r] + bias;
                h2b[(size_t)(rbase + r) * 128 + gc] = f2bf(v);
                s += v;
                ss = fmaf(v, v, ss);
            }
        }
        s += __shfl_xor(s, 16);  s += __shfl_xor(s, 32);
        ss += __shfl_xor(ss, 16); ss += __shfl_xor(ss, 32);
        if (quad == 0) { sstat2[w * 128 + gc] = s; sstat2[512 + w * 128 + gc] = ss; }
    }
    __syncthreads();
    if (t < 128) {
        atomicAdd(&acc_g[256 + t], sstat2[t] + sstat2[128 + t] + sstat2[256 + t] + sstat2[384 + t]);
        atomicAdd(&acc_g[384 + t], sstat2[512 + t] + sstat2[640 + t] + sstat2[768 + t] + sstat2[896 + t]);
    }
}

// ======== K3: X_ = relu(bn(h2b))@dw2 + db2 ; accumulate sum((X_-X)^2) ========
// 512 thr (8 waves, 2x4), tile 128M x 256N, BK=32 (4 chunks), grid (512, 2).
__global__ __launch_bounds__(512) void k_dec2(const unsigned short* __restrict__ h2b,
                                              float* acc_g,
                                              const float* __restrict__ g,
                                              const float* __restrict__ be,
                                              const float* __restrict__ w2,
                                              const float* __restrict__ b2,
                                              const float* __restrict__ X) {
    __shared__ unsigned short As[128 * 40];
    __shared__ unsigned short Bs[256 * 40];
    __shared__ float scl[128], shf[128];
    __shared__ float red[512];
    const int t = threadIdx.x;
    if (t < 128) {
        float mu = acc_g[256 + t] * (1.f / 65536.f);
        float var = fmaf(-mu, mu, acc_g[384 + t] * (1.f / 65536.f));
        float s = g[t] * rsqrtf(var + 1e-5f);
        scl[t] = s;
        shf[t] = fmaf(-mu, s, be[t]);
    }
    const int row0 = blockIdx.x << 7;
    const int col0 = blockIdx.y << 8;
    const int w = t >> 6, lane = t & 63, quad = lane >> 4, lcol = lane & 15;
    const int wm = w & 1, wn = w >> 1;
    f4a acc[4][4];
#pragma unroll
    for (int i = 0; i < 4; i++)
#pragma unroll
        for (int j = 0; j < 4; j++) acc[i][j] = (f4a){0.f, 0.f, 0.f, 0.f};
    __syncthreads();

    const int bn = t & 255, bkg = t >> 8;
    const int ar = t >> 2, akq = (t & 3) << 3;
    for (int c = 0; c < 4; ++c) {
        const int k0 = c << 5;
        if (c) __syncthreads();
        // A: bf16 h2 tile, BN+ReLU fused (one uint4 = 8 bf16 per thread per chunk)
        {
            uint4 raw = *(const uint4*)(h2b + (size_t)(row0 + ar) * 128 + k0 + akq);
            unsigned pv[4] = {raw.x, raw.y, raw.z, raw.w};
            unsigned ov[4];
#pragma unroll
            for (int j = 0; j < 4; ++j) {
                float lo, hi;
                unpack2(pv[j], lo, hi);
                int k = k0 + akq + 2 * j;
                lo = fmaxf(fmaf(lo, scl[k], shf[k]), 0.f);
                hi = fmaxf(fmaf(hi, scl[k + 1], shf[k + 1]), 0.f);
                ov[j] = pack2(lo, hi);
            }
            *(uint4*)&As[ar * 40 + akq] = make_uint4(ov[0], ov[1], ov[2], ov[3]);
        }
        // B: w2 chunk [32k][256n] -> Bs[n][k]
#pragma unroll
        for (int i = 0; i < 4; ++i) {
            int k = (bkg << 4) + (i << 2);
            const float* p = w2 + (size_t)(k0 + k) * 512 + col0 + bn;
            float a0 = p[0], a1 = p[512], a2 = p[1024], a3 = p[1536];
            *(uint2*)&Bs[bn * 40 + k] = make_uint2(pack2(a0, a1), pack2(a2, a3));
        }
        __syncthreads();
        bf8 af[4];
#pragma unroll
        for (int mt = 0; mt < 4; ++mt)
            af[mt] = *(const bf8*)&As[(wm * 64 + mt * 16 + lcol) * 40 + (quad << 3)];
#pragma unroll
        for (int nt = 0; nt < 4; ++nt) {
            const bf8 bb = *(const bf8*)&Bs[(wn * 64 + nt * 16 + lcol) * 40 + (quad << 3)];
#pragma unroll
            for (int mt = 0; mt < 4; ++mt)
                acc[mt][nt] = __builtin_amdgcn_mfma_f32_16x16x32_bf16(af[mt], bb, acc[mt][nt], 0, 0, 0);
        }
    }
    float lsum = 0.f;
#pragma unroll
    for (int nt = 0; nt < 4; ++nt) {
        const int gc = col0 + wn * 64 + nt * 16 + lcol;
        const float bias = b2[gc];
#pragma unroll
        for (int mt = 0; mt < 4; ++mt) {
            const int rbase = row0 + wm * 64 + mt * 16 + (quad << 2);
#pragma unroll
            for (int r = 0; r < 4; ++r) {
                float val = acc[mt][nt][r] + bias;
                float d = val - X[(size_t)(rbase + r) * 512 + gc];
                lsum = fmaf(d, d, lsum);
            }
        }
    }
    red[t] = lsum;
    __syncthreads();
    for (int s = 256; s > 0; s >>= 1) {
        if (t < s) red[t] += red[t + s];
        __syncthreads();
    }
    if (t == 0) atomicAdd(acc_g + 513, red[0]);
}

__global__ void k_final(const float* __restrict__ acc, float* __restrict__ out) {
    if (threadIdx.x == 0) out[0] = 2.f * acc[512] + sqrtf(acc[513]);
}

extern "C" void kernel_launch(void* const* d_in, const int* in_sizes, int n_in,
                              void* d_out, int out_size, void* d_ws, size_t ws_size,
                              hipStream_t stream) {
    const float* X       = (const float*)d_in[0];
    const float* enc_w1  = (const float*)d_in[1];
    const float* enc_b1  = (const float*)d_in[2];
    const float* enc_g1  = (const float*)d_in[3];
    const float* enc_be1 = (const float*)d_in[4];
    const float* enc_w2  = (const float*)d_in[5];
    const float* enc_b2  = (const float*)d_in[6];
    const float* dec_w1  = (const float*)d_in[7];
    const float* dec_b1  = (const float*)d_in[8];
    const float* dec_g1  = (const float*)d_in[9];
    const float* dec_be1 = (const float*)d_in[10];
    const float* dec_w2  = (const float*)d_in[11];
    const float* dec_b2  = (const float*)d_in[12];
    const float* cb      = (const float*)d_in[13];
    float* out = (float*)d_out;

    float* acc = (float*)d_ws;                               // 1024 f32
    unsigned short* cbb = (unsigned short*)(acc + 1024);     // 1024*32 bf16
    float* cn_g = (float*)(cbb + 1024 * 32);                 // 1024 f32
    float* h1 = cn_g + 1024;                                 // 65536*128 f32
    unsigned short* h2b = (unsigned short*)(h1 + (size_t)65536 * 128);  // bf16

    k_prep<<<5, 256, 0, stream>>>(cb, acc, cbb, cn_g);
    k_enc1<<<512, 256, 0, stream>>>(X, enc_w1, enc_b1, h1, acc);
    k_mid<<<512, 256, 0, stream>>>(h1, enc_w2, enc_b2, enc_g1, enc_be1,
                                   cb, cbb, cn_g, dec_w1, dec_b1, h2b, acc);
    k_dec2<<<dim3(512, 2), 512, 0, stream>>>(h2b, acc, dec_g1, dec_be1, dec_w2, dec_b2, X);
    k_final<<<1, 64, 0, stream>>>(acc, out);
}